// Round 4
// baseline (257.217 us; speedup 1.0000x reference)
//
#include <hip/hip_runtime.h>

#define B_ 4
#define T_ 4096
#define C_ 1024
#define H_ 64

typedef _Float16 half8  __attribute__((ext_vector_type(8)));
typedef _Float16 half4_ __attribute__((ext_vector_type(4)));
typedef float    floatx4 __attribute__((ext_vector_type(4)));

#define MFMA16(a, b, c) __builtin_amdgcn_mfma_f32_16x16x32_f16(a, b, c, 0, 0, 0)

// ---------------------------------------------------------------------------
// Kernel 1: pack W -> Wt[h'][c] f16, h' = 0..191 (q:0-63, k:64-127, v:128-191)
// ---------------------------------------------------------------------------
__global__ __launch_bounds__(256) void pack_w_kn(
    const float* __restrict__ Wq, const float* __restrict__ Wk,
    const float* __restrict__ Wv, _Float16* __restrict__ Wt)
{
    const int idx = blockIdx.x * 256 + threadIdx.x;   // 0 .. 192*1024-1
    const int hp = idx >> 10, c = idx & 1023;
    const float* W = (hp < 64) ? Wq : (hp < 128) ? Wk : Wv;
    Wt[idx] = (_Float16)W[c * H_ + (hp & 63)];
}

// ---------------------------------------------------------------------------
// Kernel 2: fused QKV projection, f16 MFMA, C^T = Wt * x^T.
// Block = 16 x-rows, 8 waves split 2x4 over (h'-half, C-quarter):
//   whalf = w&1  -> global mt in [whalf*6, whalf*6+6)
//   cq    = w>>1 -> C-range [cq*256, +256), 8 K-steps of 32, unroll 4
// 8192 waves = up to 24 waves/CU. C-quarters merged via LDS (3 partial sets).
// ---------------------------------------------------------------------------
__global__ __launch_bounds__(512, 6) void qkv_kn(
    const float* __restrict__ x, const _Float16* __restrict__ Wt,
    _Float16* __restrict__ Qh, _Float16* __restrict__ Kh,
    _Float16* __restrict__ Vt)
{
    __shared__ float Aw[3][2][64][24];                // 36864 B
    const int lane  = threadIdx.x & 63;
    const int w     = threadIdx.x >> 6;               // 0..7
    const int whalf = w & 1;
    const int cq    = w >> 1;                         // 0..3
    const int q     = lane >> 4, c = lane & 15;
    const int row   = blockIdx.x * 16 + c;            // lane's x-row (B-frag n)

    const float*    xp = x  + (size_t)row * C_ + cq * 256 + q * 8;
    const _Float16* wp = Wt + (size_t)(whalf * 96 + c) * C_ + cq * 256 + q * 8;

    floatx4 acc[6];
    #pragma unroll
    for (int i = 0; i < 6; ++i) acc[i] = floatx4{0.f, 0.f, 0.f, 0.f};

    #pragma unroll 4
    for (int ks = 0; ks < 8; ++ks) {
        const float4 f0 = *(const float4*)(xp + ks * 32);
        const float4 f1 = *(const float4*)(xp + ks * 32 + 4);
        half8 bx;
        bx[0] = (_Float16)f0.x; bx[1] = (_Float16)f0.y;
        bx[2] = (_Float16)f0.z; bx[3] = (_Float16)f0.w;
        bx[4] = (_Float16)f1.x; bx[5] = (_Float16)f1.y;
        bx[6] = (_Float16)f1.z; bx[7] = (_Float16)f1.w;
        #pragma unroll
        for (int mt = 0; mt < 6; ++mt) {
            const half8 a = *(const half8*)(wp + (size_t)mt * 16 * C_ + ks * 32);
            acc[mt] = MFMA16(a, bx, acc[mt]);
        }
    }

    // merge C-quarters: cq>0 write partials, cq==0 sums + epilogue
    if (cq > 0) {
        #pragma unroll
        for (int mt = 0; mt < 6; ++mt)
            *(floatx4*)&Aw[cq - 1][whalf][lane][mt * 4] = acc[mt];
    }
    __syncthreads();
    if (cq == 0) {
        #pragma unroll
        for (int mt = 0; mt < 6; ++mt) {
            acc[mt] += *(const floatx4*)&Aw[0][whalf][lane][mt * 4];
            acc[mt] += *(const floatx4*)&Aw[1][whalf][lane][mt * 4];
            acc[mt] += *(const floatx4*)&Aw[2][whalf][lane][mt * 4];
        }

        const int b = row >> 12, t = row & (T_ - 1);
        #pragma unroll
        for (int mt = 0; mt < 6; ++mt) {
            const int g = whalf * 6 + mt;             // global mt 0..11
            if (g < 4) {                              // Q: h = g*16+q*4+r
                half4_ v;
                #pragma unroll
                for (int r = 0; r < 4; ++r) v[r] = (_Float16)acc[mt][r];
                *(half4_*)(Qh + (size_t)row * H_ + g * 16 + q * 4) = v;
            } else if (g < 8) {                       // K
                half4_ v;
                #pragma unroll
                for (int r = 0; r < 4; ++r) v[r] = (_Float16)acc[mt][r];
                *(half4_*)(Kh + (size_t)row * H_ + (g - 4) * 16 + q * 4) = v;
            } else {                                  // V transposed: Vt[b][h][t]
                #pragma unroll
                for (int r = 0; r < 4; ++r) {
                    const int h2 = (g - 8) * 16 + q * 4 + r;
                    Vt[((size_t)b * H_ + h2) * T_ + t] = (_Float16)acc[mt][r];
                }
            }
        }
    }
}

// ---------------------------------------------------------------------------
// Kernel 3: causal flash attention, f16 MFMA, 8-way split-K per block.
// Block = one 16-row q-tile (512 thr); wave w handles key-tiles w, w+8, ...
// (max 8 iters).  Heavy tiles first (t = 255-bx).  No asm barriers: compiler
// inserts precise waitcnts; P double-buffered in wave-private LDS; V-frags
// loaded right after S-MFMAs so their latency hides behind softmax.
// Partial (m,l,O) merged via LDS flash combine (overlaid on P region).
// ---------------------------------------------------------------------------
__global__ __launch_bounds__(512, 4) void attn_kn(
    const _Float16* __restrict__ Qh, const _Float16* __restrict__ Kh,
    const _Float16* __restrict__ Vt, float* __restrict__ out)
{
    __shared__ __align__(16) char smem[36864];
    const int lane = threadIdx.x & 63;
    const int w    = threadIdx.x >> 6;                // 0..7
    const int q    = lane >> 4, c = lane & 15;
    const int b    = blockIdx.y;
    const int t    = 255 - (int)blockIdx.x;           // heavy tiles first
    const int row0 = t * 16;
    const int grow = b * T_ + row0;
    const int nk   = (t >> 2) + 1;                    // 64-key tiles (last=diag)

    const _Float16* Kb = Kh + (size_t)b * T_ * H_;
    const _Float16* Vb = Vt + (size_t)b * H_ * T_;
    _Float16* Pw = (_Float16*)smem + w * 2304;        // wave's 2 P buffers

    // Q B-frag: B[k=h][n=qrow].  Pre-scale by (1/8)*log2(e).
    half8 bq0 = *(const half8*)(Qh + (size_t)(grow + c) * H_ + q * 8);
    half8 bq1 = *(const half8*)(Qh + (size_t)(grow + c) * H_ + 32 + q * 8);
    const _Float16 qs = (_Float16)0.18033688f;
    bq0 *= qs; bq1 *= qs;

    floatx4 o[4];
    #pragma unroll
    for (int i = 0; i < 4; ++i) o[i] = floatx4{0.f, 0.f, 0.f, 0.f};
    float m = -3.0e38f, l = 0.f;

    for (int kt = w; kt < nk; kt += 8) {
        const int kb = kt * 64;
        half8 a0[4], a1[4];

        // K-frags
        #pragma unroll
        for (int mt = 0; mt < 4; ++mt) {
            const _Float16* kp = Kb + (size_t)(kb + mt * 16 + c) * H_ + q * 8;
            a0[mt] = *(const half8*)kp;
            a1[mt] = *(const half8*)(kp + 32);
        }
        // S^T tiles: rows = keys, col = q-row (in-lane)
        floatx4 s[4];
        #pragma unroll
        for (int mt = 0; mt < 4; ++mt) {
            floatx4 z = floatx4{0.f, 0.f, 0.f, 0.f};
            z = MFMA16(a0[mt], bq0, z);
            s[mt] = MFMA16(a1[mt], bq1, z);
        }
        // V-frags now — latency hides behind softmax (regs reused from K)
        #pragma unroll
        for (int mt = 0; mt < 4; ++mt) {
            const _Float16* vp = Vb + (size_t)(mt * 16 + c) * T_ + kb + q * 8;
            a0[mt] = *(const half8*)vp;
            a1[mt] = *(const half8*)(vp + 32);
        }

        if (kt == nk - 1) {                           // causal mask (diag tile)
            #pragma unroll
            for (int mt = 0; mt < 4; ++mt)
                #pragma unroll
                for (int r = 0; r < 4; ++r)
                    if (kb + mt * 16 + q * 4 + r > row0 + c) s[mt][r] = -3.0e38f;
        }

        // online softmax; lane holds 16 scores of ONE q-row
        float mx = s[0][0];
        #pragma unroll
        for (int mt = 0; mt < 4; ++mt)
            #pragma unroll
            for (int r = 0; r < 4; ++r) mx = fmaxf(mx, s[mt][r]);
        mx = fmaxf(mx, __shfl_xor(mx, 16, 64));
        mx = fmaxf(mx, __shfl_xor(mx, 32, 64));
        const float mn    = fmaxf(m, mx);
        const float alpha = exp2f(m - mn);
        float p[4][4];
        float sl = 0.f;
        #pragma unroll
        for (int mt = 0; mt < 4; ++mt)
            #pragma unroll
            for (int r = 0; r < 4; ++r) {
                p[mt][r] = exp2f(s[mt][r] - mn);
                sl += p[mt][r];
            }
        sl += __shfl_xor(sl, 16, 64);
        sl += __shfl_xor(sl, 32, 64);
        l = l * alpha + sl;
        m = mn;
        #pragma unroll
        for (int mt = 0; mt < 4; ++mt)
            #pragma unroll
            for (int r = 0; r < 4; ++r) o[mt][r] *= alpha;

        // P^T -> wave-private LDS (double-buffered), reload as B-frags
        _Float16* pl = Pw + ((kt >> 3) & 1) * 1152 + c * 72;
        #pragma unroll
        for (int mt = 0; mt < 4; ++mt) {
            half4_ ph;
            #pragma unroll
            for (int r = 0; r < 4; ++r) ph[r] = (_Float16)p[mt][r];
            *(half4_*)(pl + mt * 16 + q * 4) = ph;
        }
        const half8 bp0 = *(const half8*)(pl + q * 8);
        const half8 bp1 = *(const half8*)(pl + 32 + q * 8);

        // O^T += V^T · P^T
        #pragma unroll
        for (int mt = 0; mt < 4; ++mt) {
            o[mt] = MFMA16(a0[mt], bp0, o[mt]);
            o[mt] = MFMA16(a1[mt], bp1, o[mt]);
        }
    }

    // ---- flash combine across the 8 waves (overlay LDS after sync) ----
    __syncthreads();                                  // everyone done with Pw
    float* Ol = (float*)smem;                         // [8][1088]
    float* Ml = (float*)(smem + 34816);               // [8][16]
    float* Ll = (float*)(smem + 35328);               // [8][16]
    if (q == 0) Ml[w * 16 + c] = m;
    __syncthreads();
    float M = Ml[c];
    #pragma unroll
    for (int w2 = 1; w2 < 8; ++w2) M = fmaxf(M, Ml[w2 * 16 + c]);
    const float alpha = exp2f(m - M);                 // 0 for empty waves
    if (q == 0) Ll[w * 16 + c] = l * alpha;
    #pragma unroll
    for (int mt = 0; mt < 4; ++mt)
        #pragma unroll
        for (int r = 0; r < 4; ++r)
            Ol[w * 1088 + (mt * 16 + q * 4 + r) * 17 + c] = o[mt][r] * alpha;
    __syncthreads();

    float L = 0.f;
    #pragma unroll
    for (int w2 = 0; w2 < 8; ++w2) L += Ll[w2 * 16 + c];
    const float inv = 1.f / L;
    const int h0 = w * 8 + q * 2;                     // lane reduces 2 h-values
    float ox = 0.f, oy = 0.f;
    #pragma unroll
    for (int w2 = 0; w2 < 8; ++w2) {
        ox += Ol[w2 * 1088 + h0 * 17 + c];
        oy += Ol[w2 * 1088 + (h0 + 1) * 17 + c];
    }
    float2 st; st.x = ox * inv; st.y = oy * inv;
    *(float2*)(out + (size_t)(grow + c) * H_ + h0) = st;
}

extern "C" void kernel_launch(void* const* d_in, const int* in_sizes, int n_in,
                              void* d_out, int out_size, void* d_ws, size_t ws_size,
                              hipStream_t stream) {
    const float* x  = (const float*)d_in[0];
    const float* Wq = (const float*)d_in[1];
    const float* Wk = (const float*)d_in[2];
    const float* Wv = (const float*)d_in[3];
    float* out = (float*)d_out;

    _Float16* ws = (_Float16*)d_ws;
    _Float16* Wt = ws;                                //   192*1024 = 196608
    _Float16* Qh = ws + 196608;                       // 16384*64  = 1048576
    _Float16* Kh = Qh + 1048576;
    _Float16* Vt = Kh + 1048576;                      // [4][64][4096]

    hipLaunchKernelGGL(pack_w_kn, dim3(768), dim3(256), 0, stream, Wq, Wk, Wv, Wt);
    hipLaunchKernelGGL(qkv_kn, dim3((B_ * T_) / 16), dim3(512), 0, stream,
                       x, Wt, Qh, Kh, Vt);
    hipLaunchKernelGGL(attn_kn, dim3(T_ / 16, B_), dim3(512), 0, stream,
                       Qh, Kh, Vt, out);
}

// Round 5
// 214.919 us; speedup vs baseline: 1.1968x; 1.1968x over previous
//
#include <hip/hip_runtime.h>

#define B_ 4
#define T_ 4096
#define C_ 1024
#define H_ 64

typedef _Float16 half8  __attribute__((ext_vector_type(8)));
typedef _Float16 half4_ __attribute__((ext_vector_type(4)));
typedef float    floatx4 __attribute__((ext_vector_type(4)));

#define MFMA16(a, b, c) __builtin_amdgcn_mfma_f32_16x16x32_f16(a, b, c, 0, 0, 0)

// ---------------------------------------------------------------------------
// Kernel 1: pack W -> Wt[h'][c] f16, h' = 0..191 (q:0-63, k:64-127, v:128-191)
// ---------------------------------------------------------------------------
__global__ __launch_bounds__(256) void pack_w_kn(
    const float* __restrict__ Wq, const float* __restrict__ Wk,
    const float* __restrict__ Wv, _Float16* __restrict__ Wt)
{
    const int idx = blockIdx.x * 256 + threadIdx.x;   // 0 .. 192*1024-1
    const int hp = idx >> 10, c = idx & 1023;
    const float* W = (hp < 64) ? Wq : (hp < 128) ? Wk : Wv;
    Wt[idx] = (_Float16)W[c * H_ + (hp & 63)];
}

// ---------------------------------------------------------------------------
// Kernel 2: fused QKV projection, canonical LDS-staged GEMM. C^T = Wt * x^T.
// Block = 512 thr (8 waves), BM=32 x-rows, BK=64, 16 K-iters, x-tile dbuf in
// LDS (coalesced float4 read -> cvt f16 -> pad-72 store). Wave (nt,mg) owns
// n-half nt (16 rows) x 3 m-tiles (48 h').  Wt A-frags direct from L2-hot
// global, batch-loaded.  512 blocks = 16 waves/CU.
// V output re-blocked: Vtb[b][kt][h][64] (tile-contiguous for attn).
// ---------------------------------------------------------------------------
__global__ __launch_bounds__(512) void qkv_kn(
    const float* __restrict__ x, const _Float16* __restrict__ Wt,
    _Float16* __restrict__ Qh, _Float16* __restrict__ Kh,
    _Float16* __restrict__ Vtb)
{
    __shared__ _Float16 xs[2][32][72];                // 9216 B
    const int tid  = threadIdx.x;
    const int lane = tid & 63, w = tid >> 6;
    const int q    = lane >> 4, c = lane & 15;
    const int nt   = w & 1;                           // n-half (16 rows)
    const int mg   = w >> 1;                          // m-group (3 m-tiles)
    const int row0 = blockIdx.x * 32;

    // staging: thread -> (row, float4-col); wave footprint = 4 KB contiguous
    const int srow = tid >> 4, scol = (tid & 15) * 4;
    const float* xg = x + (size_t)(row0 + srow) * C_ + scol;

    const _Float16* wbase = Wt + (size_t)(mg * 48 + c) * C_ + q * 8;

    floatx4 acc[3];
    #pragma unroll
    for (int i = 0; i < 3; ++i) acc[i] = floatx4{0.f, 0.f, 0.f, 0.f};

    float4 g = *(const float4*)xg;                    // preload tile 0

    for (int j = 0; j < 16; ++j) {
        half4_ hv;
        hv[0] = (_Float16)g.x; hv[1] = (_Float16)g.y;
        hv[2] = (_Float16)g.z; hv[3] = (_Float16)g.w;
        *(half4_*)(&xs[j & 1][srow][scol]) = hv;
        __syncthreads();                              // single barrier (dbuf-safe)
        if (j < 15) g = *(const float4*)(xg + (j + 1) * 64);

        // B-frags: x^T[k][n=row] from LDS (pad-72 -> 2-way banks = free)
        const _Float16* xrow = &xs[j & 1][nt * 16 + c][q * 8];
        const half8 b0 = *(const half8*)xrow;
        const half8 b1 = *(const half8*)(xrow + 32);

        // A-frags: 6 independent 16-B loads from L2-hot Wt, then 6 MFMAs
        half8 a[6];
        #pragma unroll
        for (int i = 0; i < 3; ++i) {
            const _Float16* ap = wbase + (size_t)i * 16 * C_ + j * 64;
            a[i * 2]     = *(const half8*)ap;
            a[i * 2 + 1] = *(const half8*)(ap + 32);
        }
        #pragma unroll
        for (int i = 0; i < 3; ++i) {
            acc[i] = MFMA16(a[i * 2],     b0, acc[i]);
            acc[i] = MFMA16(a[i * 2 + 1], b1, acc[i]);
        }
    }

    // epilogue: lane holds col = its x-row (row0+nt*16+c), rows h' = g*16+q*4+r
    const int row = row0 + nt * 16 + c;
    const int b = row >> 12, t4 = row & (T_ - 1);
    #pragma unroll
    for (int i = 0; i < 3; ++i) {
        const int gi = mg * 3 + i;                    // m-tile 0..11
        if (gi < 4) {                                 // Q
            half4_ v;
            #pragma unroll
            for (int r = 0; r < 4; ++r) v[r] = (_Float16)acc[i][r];
            *(half4_*)(Qh + (size_t)row * H_ + gi * 16 + q * 4) = v;
        } else if (gi < 8) {                          // K
            half4_ v;
            #pragma unroll
            for (int r = 0; r < 4; ++r) v[r] = (_Float16)acc[i][r];
            *(half4_*)(Kh + (size_t)row * H_ + (gi - 4) * 16 + q * 4) = v;
        } else {                                      // V re-blocked
            #pragma unroll
            for (int r = 0; r < 4; ++r) {
                const int h2 = (gi - 8) * 16 + q * 4 + r;
                Vtb[(((size_t)b * 64 + (t4 >> 6)) * 64 + h2) * 64 + (t4 & 63)]
                    = (_Float16)acc[i][r];
            }
        }
    }
}

// ---------------------------------------------------------------------------
// Kernel 3: causal flash attention, f16 MFMA, 8-way split-K per block.
// Block = one 16-row q-tile (512 thr); wave w handles key-tiles w, w+8, ...
// Heavy tiles first.  V reads now tile-contiguous via Vtb[b][kt][h][64].
// Partial (m,l,O) merged via LDS flash combine (overlaid on P region).
// ---------------------------------------------------------------------------
__global__ __launch_bounds__(512, 4) void attn_kn(
    const _Float16* __restrict__ Qh, const _Float16* __restrict__ Kh,
    const _Float16* __restrict__ Vtb, float* __restrict__ out)
{
    __shared__ __align__(16) char smem[36864];
    const int lane = threadIdx.x & 63;
    const int w    = threadIdx.x >> 6;                // 0..7
    const int q    = lane >> 4, c = lane & 15;
    const int b    = blockIdx.y;
    const int t    = 255 - (int)blockIdx.x;           // heavy tiles first
    const int row0 = t * 16;
    const int grow = b * T_ + row0;
    const int nk   = (t >> 2) + 1;                    // 64-key tiles (last=diag)

    const _Float16* Kb = Kh + (size_t)b * T_ * H_;
    _Float16* Pw = (_Float16*)smem + w * 2304;        // wave's 2 P buffers

    // Q B-frag: B[k=h][n=qrow].  Pre-scale by (1/8)*log2(e).
    half8 bq0 = *(const half8*)(Qh + (size_t)(grow + c) * H_ + q * 8);
    half8 bq1 = *(const half8*)(Qh + (size_t)(grow + c) * H_ + 32 + q * 8);
    const _Float16 qs = (_Float16)0.18033688f;
    bq0 *= qs; bq1 *= qs;

    floatx4 o[4];
    #pragma unroll
    for (int i = 0; i < 4; ++i) o[i] = floatx4{0.f, 0.f, 0.f, 0.f};
    float m = -3.0e38f, l = 0.f;

    for (int kt = w; kt < nk; kt += 8) {
        const int kb = kt * 64;
        half8 a0[4], a1[4];

        // K-frags (near-coalesced: 16 rows x 64 B, sequential 128-B rows)
        #pragma unroll
        for (int mt = 0; mt < 4; ++mt) {
            const _Float16* kp = Kb + (size_t)(kb + mt * 16 + c) * H_ + q * 8;
            a0[mt] = *(const half8*)kp;
            a1[mt] = *(const half8*)(kp + 32);
        }
        // S^T tiles: rows = keys, col = q-row (in-lane)
        floatx4 s[4];
        #pragma unroll
        for (int mt = 0; mt < 4; ++mt) {
            floatx4 z = floatx4{0.f, 0.f, 0.f, 0.f};
            z = MFMA16(a0[mt], bq0, z);
            s[mt] = MFMA16(a1[mt], bq1, z);
        }
        // V-frags from tile-contiguous Vtb — latency hides behind softmax
        const _Float16* vtile = Vtb + (((size_t)b * 64 + kt) * 64) * 64;
        #pragma unroll
        for (int mt = 0; mt < 4; ++mt) {
            const _Float16* vp = vtile + (size_t)(mt * 16 + c) * 64 + q * 8;
            a0[mt] = *(const half8*)vp;
            a1[mt] = *(const half8*)(vp + 32);
        }

        if (kt == nk - 1) {                           // causal mask (diag tile)
            #pragma unroll
            for (int mt = 0; mt < 4; ++mt)
                #pragma unroll
                for (int r = 0; r < 4; ++r)
                    if (kb + mt * 16 + q * 4 + r > row0 + c) s[mt][r] = -3.0e38f;
        }

        // online softmax; lane holds 16 scores of ONE q-row
        float mx = s[0][0];
        #pragma unroll
        for (int mt = 0; mt < 4; ++mt)
            #pragma unroll
            for (int r = 0; r < 4; ++r) mx = fmaxf(mx, s[mt][r]);
        mx = fmaxf(mx, __shfl_xor(mx, 16, 64));
        mx = fmaxf(mx, __shfl_xor(mx, 32, 64));
        const float mn    = fmaxf(m, mx);
        const float alpha = exp2f(m - mn);
        float p[4][4];
        float sl = 0.f;
        #pragma unroll
        for (int mt = 0; mt < 4; ++mt)
            #pragma unroll
            for (int r = 0; r < 4; ++r) {
                p[mt][r] = exp2f(s[mt][r] - mn);
                sl += p[mt][r];
            }
        sl += __shfl_xor(sl, 16, 64);
        sl += __shfl_xor(sl, 32, 64);
        l = l * alpha + sl;
        m = mn;
        #pragma unroll
        for (int mt = 0; mt < 4; ++mt)
            #pragma unroll
            for (int r = 0; r < 4; ++r) o[mt][r] *= alpha;

        // P^T -> wave-private LDS (double-buffered), reload as B-frags
        _Float16* pl = Pw + ((kt >> 3) & 1) * 1152 + c * 72;
        #pragma unroll
        for (int mt = 0; mt < 4; ++mt) {
            half4_ ph;
            #pragma unroll
            for (int r = 0; r < 4; ++r) ph[r] = (_Float16)p[mt][r];
            *(half4_*)(pl + mt * 16 + q * 4) = ph;
        }
        const half8 bp0 = *(const half8*)(pl + q * 8);
        const half8 bp1 = *(const half8*)(pl + 32 + q * 8);

        // O^T += V^T · P^T
        #pragma unroll
        for (int mt = 0; mt < 4; ++mt) {
            o[mt] = MFMA16(a0[mt], bp0, o[mt]);
            o[mt] = MFMA16(a1[mt], bp1, o[mt]);
        }
    }

    // ---- flash combine across the 8 waves (overlay LDS after sync) ----
    __syncthreads();                                  // everyone done with Pw
    float* Ol = (float*)smem;                         // [8][1088]
    float* Ml = (float*)(smem + 34816);               // [8][16]
    float* Ll = (float*)(smem + 35328);               // [8][16]
    if (q == 0) Ml[w * 16 + c] = m;
    __syncthreads();
    float M = Ml[c];
    #pragma unroll
    for (int w2 = 1; w2 < 8; ++w2) M = fmaxf(M, Ml[w2 * 16 + c]);
    const float alpha = exp2f(m - M);                 // 0 for empty waves
    if (q == 0) Ll[w * 16 + c] = l * alpha;
    #pragma unroll
    for (int mt = 0; mt < 4; ++mt)
        #pragma unroll
        for (int r = 0; r < 4; ++r)
            Ol[w * 1088 + (mt * 16 + q * 4 + r) * 17 + c] = o[mt][r] * alpha;
    __syncthreads();

    float L = 0.f;
    #pragma unroll
    for (int w2 = 0; w2 < 8; ++w2) L += Ll[w2 * 16 + c];
    const float inv = 1.f / L;
    const int h0 = w * 8 + q * 2;                     // lane reduces 2 h-values
    float ox = 0.f, oy = 0.f;
    #pragma unroll
    for (int w2 = 0; w2 < 8; ++w2) {
        ox += Ol[w2 * 1088 + h0 * 17 + c];
        oy += Ol[w2 * 1088 + (h0 + 1) * 17 + c];
    }
    float2 st; st.x = ox * inv; st.y = oy * inv;
    *(float2*)(out + (size_t)(grow + c) * H_ + h0) = st;
}

extern "C" void kernel_launch(void* const* d_in, const int* in_sizes, int n_in,
                              void* d_out, int out_size, void* d_ws, size_t ws_size,
                              hipStream_t stream) {
    const float* x  = (const float*)d_in[0];
    const float* Wq = (const float*)d_in[1];
    const float* Wk = (const float*)d_in[2];
    const float* Wv = (const float*)d_in[3];
    float* out = (float*)d_out;

    _Float16* ws = (_Float16*)d_ws;
    _Float16* Wt  = ws;                               //   192*1024 = 196608
    _Float16* Qh  = ws + 196608;                      // 16384*64  = 1048576
    _Float16* Kh  = Qh + 1048576;
    _Float16* Vtb = Kh + 1048576;                     // [4][64][64][64]

    hipLaunchKernelGGL(pack_w_kn, dim3(768), dim3(256), 0, stream, Wq, Wk, Wv, Wt);
    hipLaunchKernelGGL(qkv_kn, dim3((B_ * T_) / 32), dim3(512), 0, stream,
                       x, Wt, Qh, Kh, Vtb);
    hipLaunchKernelGGL(attn_kn, dim3(T_ / 16, B_), dim3(512), 0, stream,
                       Qh, Kh, Vtb, out);
}

// Round 6
// 142.686 us; speedup vs baseline: 1.8027x; 1.5062x over previous
//
#include <hip/hip_runtime.h>

#define B_ 4
#define T_ 4096
#define C_ 1024
#define H_ 64

typedef _Float16 half8  __attribute__((ext_vector_type(8)));
typedef _Float16 half4_ __attribute__((ext_vector_type(4)));
typedef float    floatx4 __attribute__((ext_vector_type(4)));

#define MFMA16(a, b, c) __builtin_amdgcn_mfma_f32_16x16x32_f16(a, b, c, 0, 0, 0)

// ---------------------------------------------------------------------------
// Kernel 1: pack W into MFMA-fragment order (lane-contiguous A-frags):
// Wt2[((mt*16 + j)*2 + f)*64 + lane]*8 + jj  <-  W[k][h'],
//   k = j*64 + f*32 + (lane>>4)*8 + jj,  h' = mt*16 + (lane&15)  (mt 0..11)
// A-frag load in qkv becomes one coalesced 1-KB instruction per wave.
// ---------------------------------------------------------------------------
__global__ __launch_bounds__(256) void pack_w_kn(
    const float* __restrict__ Wq, const float* __restrict__ Wk,
    const float* __restrict__ Wv, _Float16* __restrict__ Wt2)
{
    const int idx  = blockIdx.x * 256 + threadIdx.x;  // 0 .. 196607
    const int mt   = idx >> 14;
    const int j    = (idx >> 10) & 15;
    const int f    = (idx >> 9) & 1;
    const int lane = (idx >> 3) & 63;
    const int jj   = idx & 7;
    const int q = lane >> 4, c = lane & 15;
    const int k  = j * 64 + f * 32 + q * 8 + jj;
    const int hp = mt * 16 + c;                       // 0..191
    const float* W = (hp < 64) ? Wq : (hp < 128) ? Wk : Wv;
    Wt2[idx] = (_Float16)W[k * H_ + (hp & 63)];
}

// ---------------------------------------------------------------------------
// Kernel 2: fused QKV projection, LDS-staged x + packed-Wt A-frags.
// Block = 512 thr, BM=32 rows, 16 K-steps of 64.  Wave (nt, mg): n-half nt,
// m-group mg (3 m-tiles).  Outputs: Qh row-major; K and V written directly in
// per-64-key-tile FRAGMENT-PACKED layouts (8 KB tiles):
//   Kpk[b][kt]: frag(mt,f) elem = K[key=mt*16+c][h=f*32+q*8+j] at
//               ((mt*2+f)*64 + lane)*8 + j
//   Vpk[b][kt]: frag(mt,f) elem = V^T[h=mt*16+c][key=f*32+q*8+j], same form.
// ---------------------------------------------------------------------------
__global__ __launch_bounds__(512) void qkv_kn(
    const float* __restrict__ x, const _Float16* __restrict__ Wt2,
    _Float16* __restrict__ Qh, _Float16* __restrict__ Kpk,
    _Float16* __restrict__ Vpk)
{
    __shared__ _Float16 xs[2][32][72];                // 9216 B
    const int tid  = threadIdx.x;
    const int lane = tid & 63, w = tid >> 6;
    const int q    = lane >> 4, c = lane & 15;
    const int nt   = w & 1;                           // n-half (16 rows)
    const int mg   = w >> 1;                          // m-group (3 m-tiles)
    const int row0 = blockIdx.x * 32;

    const int srow = tid >> 4, scol = (tid & 15) * 4;
    const float* xg = x + (size_t)(row0 + srow) * C_ + scol;

    floatx4 acc[3];
    #pragma unroll
    for (int i = 0; i < 3; ++i) acc[i] = floatx4{0.f, 0.f, 0.f, 0.f};

    float4 g = *(const float4*)xg;                    // preload tile 0

    for (int j = 0; j < 16; ++j) {
        half4_ hv;
        hv[0] = (_Float16)g.x; hv[1] = (_Float16)g.y;
        hv[2] = (_Float16)g.z; hv[3] = (_Float16)g.w;
        *(half4_*)(&xs[j & 1][srow][scol]) = hv;
        __syncthreads();
        if (j < 15) g = *(const float4*)(xg + (j + 1) * 64);

        const _Float16* xrow = &xs[j & 1][nt * 16 + c][q * 8];
        const half8 b0 = *(const half8*)xrow;
        const half8 b1 = *(const half8*)(xrow + 32);

        // A-frags: 6 lane-contiguous 1-KB loads from L2-hot packed Wt2
        half8 a[6];
        #pragma unroll
        for (int i = 0; i < 3; ++i) {
            const size_t fb = ((size_t)((mg * 3 + i) * 16 + j) * 2) * 512 + lane * 8;
            a[i * 2]     = *(const half8*)(Wt2 + fb);
            a[i * 2 + 1] = *(const half8*)(Wt2 + fb + 512);
        }
        #pragma unroll
        for (int i = 0; i < 3; ++i) {
            acc[i] = MFMA16(a[i * 2],     b0, acc[i]);
            acc[i] = MFMA16(a[i * 2 + 1], b1, acc[i]);
        }
    }

    // epilogue: lane col = x-row (row0+nt*16+c); rows h' = gi*16+q*4+r
    const int row = row0 + nt * 16 + c;
    const int b = row >> 12, t4 = row & (T_ - 1);
    const int kt = t4 >> 6;
    const size_t tbase = ((size_t)b * 64 + kt) * 4096;
    const int mtk = (t4 >> 4) & 3;                    // key-tile m-row group
    const int kk  = t4 & 63;                          // key pos in tile

    #pragma unroll
    for (int i = 0; i < 3; ++i) {
        const int gi = mg * 3 + i;                    // m-tile 0..11
        if (gi < 4) {                                 // Q row-major
            half4_ v;
            #pragma unroll
            for (int r = 0; r < 4; ++r) v[r] = (_Float16)acc[i][r];
            *(half4_*)(Qh + (size_t)row * H_ + gi * 16 + q * 4) = v;
        } else if (gi < 8) {                          // K fragment-packed
            half4_ v;
            #pragma unroll
            for (int r = 0; r < 4; ++r) v[r] = (_Float16)acc[i][r];
            const int e  = gi - 4;                    // h = e*16 + q*4 + r
            const int f  = e >> 1;
            const int qa = (e * 2 + (q >> 1)) & 3;
            *(half4_*)(Kpk + tbase + ((size_t)(mtk * 2 + f) * 64 + qa * 16 + c) * 8
                       + (q & 1) * 4) = v;
        } else {                                      // V fragment-packed
            const int mtv = gi - 8;
            const int qa = (kk >> 3) & 3, fv = kk >> 5, jv = kk & 7;
            #pragma unroll
            for (int r = 0; r < 4; ++r) {
                const int cv = q * 4 + r;             // h & 15
                Vpk[tbase + ((size_t)(mtv * 2 + fv) * 64 + qa * 16 + cv) * 8 + jv]
                    = (_Float16)acc[i][r];
            }
        }
    }
}

// ---------------------------------------------------------------------------
// Kernel 3: causal flash attention, 8-way in-block split-K (round-5
// structure) with fragment-packed K/V: every frag load is base + lane*16 —
// one coalesced 1-KB L2 transaction (TA divergence eliminated).
// ---------------------------------------------------------------------------
__global__ __launch_bounds__(512, 4) void attn_kn(
    const _Float16* __restrict__ Qh, const _Float16* __restrict__ Kpk,
    const _Float16* __restrict__ Vpk, float* __restrict__ out)
{
    __shared__ __align__(16) char smem[36864];
    const int lane = threadIdx.x & 63;
    const int w    = threadIdx.x >> 6;                // 0..7
    const int q    = lane >> 4, c = lane & 15;
    const int b    = blockIdx.y;
    const int t    = 255 - (int)blockIdx.x;           // heavy tiles first
    const int row0 = t * 16;
    const int grow = b * T_ + row0;
    const int nk   = (t >> 2) + 1;                    // 64-key tiles (last=diag)

    _Float16* Pw = (_Float16*)smem + w * 2304;        // wave's 2 P buffers

    // Q B-frag: B[k=h][n=qrow].  Pre-scale by (1/8)*log2(e).
    half8 bq0 = *(const half8*)(Qh + (size_t)(grow + c) * H_ + q * 8);
    half8 bq1 = *(const half8*)(Qh + (size_t)(grow + c) * H_ + 32 + q * 8);
    const _Float16 qs = (_Float16)0.18033688f;
    bq0 *= qs; bq1 *= qs;

    floatx4 o[4];
    #pragma unroll
    for (int i = 0; i < 4; ++i) o[i] = floatx4{0.f, 0.f, 0.f, 0.f};
    float m = -3.0e38f, l = 0.f;

    for (int kt = w; kt < nk; kt += 8) {
        const int kb = kt * 64;
        const _Float16* Kt = Kpk + ((size_t)b * 64 + kt) * 4096;
        const _Float16* Vt = Vpk + ((size_t)b * 64 + kt) * 4096;
        half8 a0[4], a1[4];

        // K-frags: lane-contiguous packed loads
        #pragma unroll
        for (int mt = 0; mt < 4; ++mt) {
            a0[mt] = *(const half8*)(Kt + ((size_t)(mt * 2)     * 64 + lane) * 8);
            a1[mt] = *(const half8*)(Kt + ((size_t)(mt * 2 + 1) * 64 + lane) * 8);
        }
        floatx4 s[4];
        #pragma unroll
        for (int mt = 0; mt < 4; ++mt) {
            floatx4 z = floatx4{0.f, 0.f, 0.f, 0.f};
            z = MFMA16(a0[mt], bq0, z);
            s[mt] = MFMA16(a1[mt], bq1, z);
        }
        // V-frags issued now; latency hides behind softmax
        #pragma unroll
        for (int mt = 0; mt < 4; ++mt) {
            a0[mt] = *(const half8*)(Vt + ((size_t)(mt * 2)     * 64 + lane) * 8);
            a1[mt] = *(const half8*)(Vt + ((size_t)(mt * 2 + 1) * 64 + lane) * 8);
        }

        if (kt == nk - 1) {                           // causal mask (diag tile)
            #pragma unroll
            for (int mt = 0; mt < 4; ++mt)
                #pragma unroll
                for (int r = 0; r < 4; ++r)
                    if (kb + mt * 16 + q * 4 + r > row0 + c) s[mt][r] = -3.0e38f;
        }

        // online softmax; lane holds 16 scores of ONE q-row
        float mx = s[0][0];
        #pragma unroll
        for (int mt = 0; mt < 4; ++mt)
            #pragma unroll
            for (int r = 0; r < 4; ++r) mx = fmaxf(mx, s[mt][r]);
        mx = fmaxf(mx, __shfl_xor(mx, 16, 64));
        mx = fmaxf(mx, __shfl_xor(mx, 32, 64));
        const float mn    = fmaxf(m, mx);
        const float alpha = exp2f(m - mn);
        float p[4][4];
        float sl = 0.f;
        #pragma unroll
        for (int mt = 0; mt < 4; ++mt)
            #pragma unroll
            for (int r = 0; r < 4; ++r) {
                p[mt][r] = exp2f(s[mt][r] - mn);
                sl += p[mt][r];
            }
        sl += __shfl_xor(sl, 16, 64);
        sl += __shfl_xor(sl, 32, 64);
        l = l * alpha + sl;
        m = mn;
        #pragma unroll
        for (int mt = 0; mt < 4; ++mt)
            #pragma unroll
            for (int r = 0; r < 4; ++r) o[mt][r] *= alpha;

        // P^T -> wave-private LDS (double-buffered), reload as B-frags
        _Float16* pl = Pw + ((kt >> 3) & 1) * 1152 + c * 72;
        #pragma unroll
        for (int mt = 0; mt < 4; ++mt) {
            half4_ ph;
            #pragma unroll
            for (int r = 0; r < 4; ++r) ph[r] = (_Float16)p[mt][r];
            *(half4_*)(pl + mt * 16 + q * 4) = ph;
        }
        const half8 bp0 = *(const half8*)(pl + q * 8);
        const half8 bp1 = *(const half8*)(pl + 32 + q * 8);

        // O^T += V^T · P^T
        #pragma unroll
        for (int mt = 0; mt < 4; ++mt) {
            o[mt] = MFMA16(a0[mt], bp0, o[mt]);
            o[mt] = MFMA16(a1[mt], bp1, o[mt]);
        }
    }

    // ---- flash combine across the 8 waves (overlay LDS after sync) ----
    __syncthreads();
    float* Ol = (float*)smem;                         // [8][1088]
    float* Ml = (float*)(smem + 34816);               // [8][16]
    float* Ll = (float*)(smem + 35328);               // [8][16]
    if (q == 0) Ml[w * 16 + c] = m;
    __syncthreads();
    float M = Ml[c];
    #pragma unroll
    for (int w2 = 1; w2 < 8; ++w2) M = fmaxf(M, Ml[w2 * 16 + c]);
    const float alpha = exp2f(m - M);                 // 0 for empty waves
    if (q == 0) Ll[w * 16 + c] = l * alpha;
    #pragma unroll
    for (int mt = 0; mt < 4; ++mt)
        #pragma unroll
        for (int r = 0; r < 4; ++r)
            Ol[w * 1088 + (mt * 16 + q * 4 + r) * 17 + c] = o[mt][r] * alpha;
    __syncthreads();

    float L = 0.f;
    #pragma unroll
    for (int w2 = 0; w2 < 8; ++w2) L += Ll[w2 * 16 + c];
    const float inv = 1.f / L;
    const int h0 = w * 8 + q * 2;
    float ox = 0.f, oy = 0.f;
    #pragma unroll
    for (int w2 = 0; w2 < 8; ++w2) {
        ox += Ol[w2 * 1088 + h0 * 17 + c];
        oy += Ol[w2 * 1088 + (h0 + 1) * 17 + c];
    }
    float2 st; st.x = ox * inv; st.y = oy * inv;
    *(float2*)(out + (size_t)(grow + c) * H_ + h0) = st;
}

extern "C" void kernel_launch(void* const* d_in, const int* in_sizes, int n_in,
                              void* d_out, int out_size, void* d_ws, size_t ws_size,
                              hipStream_t stream) {
    const float* x  = (const float*)d_in[0];
    const float* Wq = (const float*)d_in[1];
    const float* Wk = (const float*)d_in[2];
    const float* Wv = (const float*)d_in[3];
    float* out = (float*)d_out;

    _Float16* ws = (_Float16*)d_ws;
    _Float16* Wt2 = ws;                               //   192*1024 = 196608
    _Float16* Qh  = ws + 196608;                      // 16384*64  = 1048576
    _Float16* Kpk = Qh + 1048576;                     // [4][64][4096]
    _Float16* Vpk = Kpk + 1048576;                    // [4][64][4096]

    hipLaunchKernelGGL(pack_w_kn, dim3(768), dim3(256), 0, stream, Wq, Wk, Wv, Wt2);
    hipLaunchKernelGGL(qkv_kn, dim3((B_ * T_) / 32), dim3(512), 0, stream,
                       x, Wt2, Qh, Kpk, Vpk);
    hipLaunchKernelGGL(attn_kn, dim3(T_ / 16, B_), dim3(512), 0, stream,
                       Qh, Kpk, Vpk, out);
}